// Round 1
// baseline (185.678 us; speedup 1.0000x reference)
//
#include <hip/hip_runtime.h>

#define LOG2E 1.4426950408889634f
#define NEGV  (-10000000000.0f)

// fast tanh: tanh(x) = 1 - 2/(exp(2x)+1); v_exp + v_rcp based, ~1e-6 abs err
__device__ __forceinline__ float fast_tanh(float x) {
  float e = __expf(2.0f * x);
  return 1.0f - __fdividef(2.0f, e + 1.0f);
}

// ---------------------------------------------------------------------------
// C[m][n] = sum_d A[m*lda+d] * B[n*ldb+d] (+ bias[n]); both operands row-major
// along d ("NT" gemm). 64x64 tile, BK=16, 256 threads, 4x4 micro-tile.
// blockIdx.z batches B/C via bz/cz strides.
// ---------------------------------------------------------------------------
#define BM 64
#define BN 64
#define BK 16

__global__ __launch_bounds__(256) void gemm_nt(
    const float* __restrict__ A, int lda,
    const float* __restrict__ B, int ldb,
    float* __restrict__ C, int ldc,
    int K, const float* __restrict__ bias,
    long bz, long cz)
{
  B += (long)blockIdx.z * bz;
  C += (long)blockIdx.z * cz;

  __shared__ float sA[BK][BM + 4];
  __shared__ float sB[BK][BN + 4];

  const int t  = threadIdx.x;
  const int bm = blockIdx.x * BM;
  const int bn = blockIdx.y * BN;
  const int ty = t >> 4, tx = t & 15;

  float acc[4][4] = {};

  for (int k0 = 0; k0 < K; k0 += BK) {
#pragma unroll
    for (int i = 0; i < 4; i++) {
      int e  = t + i * 256;
      int r  = e >> 4;       // row within tile
      int kk = e & 15;       // k within chunk
      sA[kk][r] = A[(size_t)(bm + r) * lda + k0 + kk];
      sB[kk][r] = B[(size_t)(bn + r) * ldb + k0 + kk];
    }
    __syncthreads();
#pragma unroll
    for (int kk = 0; kk < BK; kk++) {
      float ar[4], br[4];
#pragma unroll
      for (int i = 0; i < 4; i++) ar[i] = sA[kk][ty * 4 + i];
#pragma unroll
      for (int j = 0; j < 4; j++) br[j] = sB[kk][tx * 4 + j];
#pragma unroll
      for (int i = 0; i < 4; i++)
#pragma unroll
        for (int j = 0; j < 4; j++) acc[i][j] += ar[i] * br[j];
    }
    __syncthreads();
  }

#pragma unroll
  for (int i = 0; i < 4; i++) {
    int m = bm + ty * 4 + i;
#pragma unroll
    for (int j = 0; j < 4; j++) {
      int n = bn + tx * 4 + j;
      float bv = bias ? bias[n] : 0.0f;
      C[(size_t)m * ldc + n] = acc[i][j] + bv;
    }
  }
}

// ---------------------------------------------------------------------------
// column sums of kv per batch: kvsum[b][d] = sum_k kv[b][k][d]
// grid (8 b, 8 ktiles), 256 threads; atomicAdd partials.
// ---------------------------------------------------------------------------
__global__ __launch_bounds__(256) void kv_colsum(
    const float* __restrict__ kv, float* __restrict__ kvsum)
{
  const int b = blockIdx.x, kt = blockIdx.y;
  const int t = threadIdx.x;
  const float* p = kv + ((size_t)b * 512 + kt * 64) * 512;
  float s0 = 0.f, s1 = 0.f;
#pragma unroll 8
  for (int k = 0; k < 64; k++) {
    s0 += p[(size_t)k * 512 + t];
    s1 += p[(size_t)k * 512 + t + 256];
  }
  atomicAdd(&kvsum[b * 512 + t], s0);
  atomicAdd(&kvsum[b * 512 + t + 256], s1);
}

// ---------------------------------------------------------------------------
// fused score + softmax + PV. One block per (b, pair of q rows).
// 256 threads; thread t owns k = t and k = t+256 for scores, d = t and d+256
// for the output. Masked-q rows -> mean(kv[b]) (uniform softmax over all K).
// ---------------------------------------------------------------------------
__global__ __launch_bounds__(256) void attn_fused(
    const float* __restrict__ qp,     // [B*128][256] (bias already added)
    const float* __restrict__ kpT,    // [B][256][512]  (a-major, k contiguous)
    const float* __restrict__ kvsum,  // [B][512] raw column sums
    const float* __restrict__ kv,     // [B][512][512]
    const float* __restrict__ v,      // [256]
    const int* __restrict__ qlen_p,
    const int* __restrict__ klen_p,
    float* __restrict__ out)          // [B][128][512]
{
  const int K = 512, DA = 256, DV = 512, Q = 128;
  const int b  = blockIdx.y;
  const int q0 = blockIdx.x * 2;
  const int t  = threadIdx.x;
  const int qlen = qlen_p[b];
  const int klen = klen_p[b];
  const bool act0 = q0 < qlen;
  const bool act1 = (q0 + 1) < qlen;

  float* outb = out + ((size_t)b * Q + q0) * DV;

  if (!act0) {  // both rows masked (act0==false implies act1==false)
    float m0 = kvsum[b * DV + t]       * (1.0f / 512.0f);
    float m1 = kvsum[b * DV + t + 256] * (1.0f / 512.0f);
    outb[t] = m0;       outb[t + 256] = m1;
    outb[DV + t] = m0;  outb[DV + t + 256] = m1;
    return;
  }

  __shared__ float sQ0[256], sQ1[256], sV[256];
  __shared__ float sW0[512], sW1[512];
  __shared__ float redA[256], redB[256];

  sQ0[t] = qp[((size_t)b * Q + q0) * DA + t];
  sQ1[t] = qp[((size_t)b * Q + q0 + 1) * DA + t];
  sV[t]  = v[t];
  __syncthreads();

  const float* kpTb = kpT + (size_t)b * DA * K;
  const float* kvb  = kv + (size_t)b * K * DV;

  float sc00 = NEGV, sc01 = NEGV;   // row q0, k = t / t+256
  float sc10 = NEGV, sc11 = NEGV;   // row q0+1

  if (act1) {
#pragma unroll
    for (int s = 0; s < 2; s++) {
      int k = t + s * 256;
      if (k < klen) {
        float a0 = 0.f, a1 = 0.f;
#pragma unroll 8
        for (int a = 0; a < DA; a++) {
          float kpv = kpTb[(size_t)a * K + k];
          float vv  = sV[a];
          a0 += vv * fast_tanh(sQ0[a] + kpv);
          a1 += vv * fast_tanh(sQ1[a] + kpv);
        }
        if (s == 0) { sc00 = a0; sc10 = a1; }
        else        { sc01 = a0; sc11 = a1; }
      }
    }
  } else {
#pragma unroll
    for (int s = 0; s < 2; s++) {
      int k = t + s * 256;
      if (k < klen) {
        float a0 = 0.f;
#pragma unroll 8
        for (int a = 0; a < DA; a++) {
          float kpv = kpTb[(size_t)a * K + k];
          a0 += sV[a] * fast_tanh(sQ0[a] + kpv);
        }
        if (s == 0) sc00 = a0; else sc01 = a0;
      }
    }
  }

  // ---- block softmax over 512 scores, rows done simultaneously ----
  redA[t] = fmaxf(sc00, sc01);
  redB[t] = fmaxf(sc10, sc11);
  __syncthreads();
  for (int s = 128; s > 0; s >>= 1) {
    if (t < s) {
      redA[t] = fmaxf(redA[t], redA[t + s]);
      redB[t] = fmaxf(redB[t], redB[t + s]);
    }
    __syncthreads();
  }
  const float M0 = redA[0], M1 = redB[0];
  __syncthreads();

  float e00 = __expf(sc00 - M0), e01 = __expf(sc01 - M0);
  float e10 = __expf(sc10 - M1), e11 = __expf(sc11 - M1);

  redA[t] = e00 + e01;
  redB[t] = e10 + e11;
  __syncthreads();
  for (int s = 128; s > 0; s >>= 1) {
    if (t < s) {
      redA[t] += redA[t + s];
      redB[t] += redB[t + s];
    }
    __syncthreads();
  }
  const float S0 = redA[0], S1 = redB[0];
  __syncthreads();

  const float r0 = __fdividef(1.0f, S0);
  const float r1 = __fdividef(1.0f, S1);
  sW0[t] = e00 * r0;  sW0[t + 256] = e01 * r0;
  sW1[t] = e10 * r1;  sW1[t + 256] = e11 * r1;
  __syncthreads();

  // ---- PV: out[q][d] = sum_k w[k] * kv[k][d]; thread owns d = t, t+256 ----
  if (act1) {
    float a00 = 0.f, a01 = 0.f, a10 = 0.f, a11 = 0.f;
#pragma unroll 4
    for (int k = 0; k < klen; k++) {
      float w0 = sW0[k], w1 = sW1[k];
      float x0 = kvb[(size_t)k * DV + t];
      float x1 = kvb[(size_t)k * DV + t + 256];
      a00 += w0 * x0; a01 += w0 * x1;
      a10 += w1 * x0; a11 += w1 * x1;
    }
    outb[t] = a00;       outb[t + 256] = a01;
    outb[DV + t] = a10;  outb[DV + t + 256] = a11;
  } else {
    float a00 = 0.f, a01 = 0.f;
#pragma unroll 4
    for (int k = 0; k < klen; k++) {
      float w0 = sW0[k];
      a00 += w0 * kvb[(size_t)k * DV + t];
      a01 += w0 * kvb[(size_t)k * DV + t + 256];
    }
    outb[t] = a00; outb[t + 256] = a01;
    float m0 = kvsum[b * DV + t]       * (1.0f / 512.0f);
    float m1 = kvsum[b * DV + t + 256] * (1.0f / 512.0f);
    outb[DV + t] = m0; outb[DV + t + 256] = m1;
  }
}

// ---------------------------------------------------------------------------
extern "C" void kernel_launch(void* const* d_in, const int* in_sizes, int n_in,
                              void* d_out, int out_size, void* d_ws, size_t ws_size,
                              hipStream_t stream)
{
  const float* query = (const float*)d_in[0];  // [8][128][512]
  const float* kv    = (const float*)d_in[1];  // [8][512][512]
  const float* W     = (const float*)d_in[2];  // [256][1024]
  const float* bbias = (const float*)d_in[3];  // [256]
  const float* v     = (const float*)d_in[4];  // [256]
  const int*   qlen  = (const int*)d_in[5];    // [8]
  const int*   klen  = (const int*)d_in[6];    // [8]
  float* out = (float*)d_out;                  // [8][128][512]

  float* qp    = (float*)d_ws;            // 1024*256       = 1 MB
  float* kpT   = qp + 1024 * 256;         // 8*256*512      = 4 MB
  float* kvsum = kpT + 8 * 256 * 512;     // 8*512          = 16 KB

  hipMemsetAsync(kvsum, 0, 8 * 512 * sizeof(float), stream);

  // qp = query @ Wq^T + b : M=1024, N=256, K=512
  gemm_nt<<<dim3(1024 / BM, 256 / BN, 1), 256, 0, stream>>>(
      query, 512, W, 1024, qp, 256, 512, bbias, 0, 0);

  // kpT[b][a][k] = Wk @ kv[b]^T : M=256(a), N=512(k), K=512, z=b
  gemm_nt<<<dim3(256 / BM, 512 / BN, 8), 256, 0, stream>>>(
      W + 512, 1024, kv, 512, kpT, 512, 512, nullptr,
      (long)512 * 512, (long)256 * 512);

  kv_colsum<<<dim3(8, 8), 256, 0, stream>>>(kv, kvsum);

  attn_fused<<<dim3(64, 8), 256, 0, stream>>>(
      qp, kpT, kvsum, kv, v, qlen, klen, out);
}

// Round 2
// 147.705 us; speedup vs baseline: 1.2571x; 1.2571x over previous
//
#include <hip/hip_runtime.h>

#define NEGV (-10000000000.0f)

#define BM 64
#define BN 64
#define BK 16

// ---------------------------------------------------------------------------
// async global->LDS, 16B per lane. LDS dest is wave-uniform base + lane*16.
// ---------------------------------------------------------------------------
__device__ __forceinline__ void gload16(const float* g, float* l) {
  __builtin_amdgcn_global_load_lds(
      (const __attribute__((address_space(1))) void*)g,
      (__attribute__((address_space(3))) void*)l, 16, 0, 0);
}

// stage 16 rows x 512 f32 (32KB, contiguous) into LDS. 256 threads, 8 segs each.
__device__ __forceinline__ void stage32k(const float* __restrict__ gsrc,
                                         float* __restrict__ ldst, int t) {
  const int w = t >> 6, l = t & 63;
#pragma unroll
  for (int i = 0; i < 8; i++) {
    const int segw = (w * 8 + i) * 64;          // wave-uniform segment base
    gload16(gsrc + (size_t)(segw + l) * 4, ldst + (size_t)segw * 4);
  }
}

// ---------------------------------------------------------------------------
// 64x64 f32 tile gemm core: C[m][n] = (sum_d A[m][d]*B[n][d] + bias[n]) * 2
// ---------------------------------------------------------------------------
__device__ __forceinline__ void gemm64(
    const float* __restrict__ A, int lda,
    const float* __restrict__ B, int ldb,
    float* __restrict__ C, int ldc,
    const float* __restrict__ bias,
    int bm, int bn, int t,
    float (*sA)[BM + 4], float (*sB)[BN + 4])
{
  const int ty = t >> 4, tx = t & 15;
  float acc[4][4] = {};

  for (int k0 = 0; k0 < 512; k0 += BK) {
#pragma unroll
    for (int i = 0; i < 4; i++) {
      int e  = t + i * 256;
      int r  = e >> 4;
      int kk = e & 15;
      sA[kk][r] = A[(size_t)(bm + r) * lda + k0 + kk];
      sB[kk][r] = B[(size_t)(bn + r) * ldb + k0 + kk];
    }
    __syncthreads();
#pragma unroll
    for (int kk = 0; kk < BK; kk++) {
      float ar[4], br[4];
#pragma unroll
      for (int i = 0; i < 4; i++) ar[i] = sA[kk][ty * 4 + i];
#pragma unroll
      for (int j = 0; j < 4; j++) br[j] = sB[kk][tx * 4 + j];
#pragma unroll
      for (int i = 0; i < 4; i++)
#pragma unroll
        for (int j = 0; j < 4; j++) acc[i][j] += ar[i] * br[j];
    }
    __syncthreads();
  }

#pragma unroll
  for (int i = 0; i < 4; i++) {
    int m = bm + ty * 4 + i;
#pragma unroll
    for (int j = 0; j < 4; j++) {
      int n = bn + tx * 4 + j;
      float bv = bias ? bias[n] : 0.0f;
      C[(size_t)m * ldc + n] = (acc[i][j] + bv) * 2.0f;   // pre-double for exp(2x)
    }
  }
}

// one launch for both projections. blocks 0..63: qp. 64..319: kpT (8 batches).
__global__ __launch_bounds__(256) void proj_gemm(
    const float* __restrict__ query, const float* __restrict__ kv,
    const float* __restrict__ W, const float* __restrict__ bias,
    float* __restrict__ qp, float* __restrict__ kpT)
{
  __shared__ float sA[BK][BM + 4];
  __shared__ float sB[BK][BN + 4];
  const int id = blockIdx.x;
  const int t  = threadIdx.x;
  if (id < 64) {
    // qp[m][a] = (query[m][:]·Wq[a][:] + b[a])*2 ; M=1024, N=256
    gemm64(query, 512, W, 1024, qp, 256, bias,
           (id & 15) * 64, (id >> 4) * 64, t, sA, sB);
  } else {
    int r = id - 64;
    int b = r >> 5, w = r & 31;
    // kpT[b][a][k] = (Wk[a][:]·kv[b][k][:])*2 ; M=256(a), N=512(k)
    gemm64(W + 512, 1024, kv + (size_t)b * 512 * 512, 512,
           kpT + (size_t)b * 256 * 512, 512, nullptr,
           (w & 3) * 64, (w >> 2) * 64, t, sA, sB);
  }
}

// ---------------------------------------------------------------------------
// kvsum[b][d] = sum_k kv[b][k][d]
// ---------------------------------------------------------------------------
__global__ __launch_bounds__(256) void kv_colsum(
    const float* __restrict__ kv, float* __restrict__ kvsum)
{
  const int b = blockIdx.x, kt = blockIdx.y;
  const int t = threadIdx.x;
  const float* p = kv + ((size_t)b * 512 + kt * 64) * 512;
  float s0 = 0.f, s1 = 0.f;
#pragma unroll 8
  for (int k = 0; k < 64; k++) {
    s0 += p[(size_t)k * 512 + t];
    s1 += p[(size_t)k * 512 + t + 256];
  }
  atomicAdd(&kvsum[b * 512 + t], s0);
  atomicAdd(&kvsum[b * 512 + t + 256], s1);
}

// ---------------------------------------------------------------------------
// fused score + softmax + PV. Block = (b, q-pair). 256 threads.
// score phase:  tq = t>>7 (q row), tk = t&127 (k-quad 4tk..4tk+3)
// PV phase:     tq = t>>7 (q row), td4 = (t&127)*4 (d-quad)
// kpT chunks (16 a x 512 k) and kv chunks (16 k x 512 d) double-buffered in LDS
// via global_load_lds prefetch.
// score'[q,k] = -sum_a 2 v[a] / (1 + e^{2(qp+kp)}), equals true score minus
// sum_a v[a] (constant over k) -> identical softmax.
// ---------------------------------------------------------------------------
__global__ __launch_bounds__(256) void attn_fused(
    const float* __restrict__ qp,     // [B*128][256], pre-doubled, bias included
    const float* __restrict__ kpT,    // [B][256][512], pre-doubled
    const float* __restrict__ kvsum,  // [B][512]
    const float* __restrict__ kv,     // [B][512][512]
    const float* __restrict__ v,      // [256]
    const int* __restrict__ qlen_p,
    const int* __restrict__ klen_p,
    float* __restrict__ out)          // [B][128][512]
{
  const int b  = blockIdx.y;
  const int q0 = blockIdx.x * 2;
  const int t  = threadIdx.x;
  const int qlen = qlen_p[b];
  const int klen = klen_p[b];
  const bool act1 = (q0 + 1) < qlen;

  const int tq  = t >> 7;
  const int tk  = t & 127;
  const int td4 = (t & 127) * 4;

  float* outb = out + ((size_t)b * 128 + q0) * 512;

  if (q0 >= qlen) {  // both rows masked -> mean(kv[b])
    float4 m = *(const float4*)&kvsum[b * 512 + td4];
    m.x *= (1.0f / 512.0f); m.y *= (1.0f / 512.0f);
    m.z *= (1.0f / 512.0f); m.w *= (1.0f / 512.0f);
    *(float4*)&outb[(size_t)tq * 512 + td4] = m;
    return;
  }

  __shared__ __align__(16) float kbuf[2][16 * 512];   // 64KB
  __shared__ float sQ2[2][256];
  __shared__ float sV2[256];
  __shared__ float sW[2][512];
  __shared__ float red[8];

  sQ2[0][t] = qp[((size_t)b * 128 + q0) * 256 + t];
  sQ2[1][t] = qp[((size_t)b * 128 + q0 + 1) * 256 + t];
  sV2[t]    = 2.0f * v[t];

  const float* kpTb = kpT + (size_t)b * 256 * 512;
  const float* kvb  = kv + (size_t)b * 512 * 512;

  // ---- score phase ----
  stage32k(kpTb, kbuf[0], t);
  __syncthreads();   // also covers sQ2/sV2

  float sc[4] = {NEGV, NEGV, NEGV, NEGV};
  const bool kact = (4 * tk) < klen;

  int cur = 0;
#pragma unroll 1
  for (int c = 0; c < 16; c++) {
    if (c < 15) stage32k(kpTb + (size_t)(c + 1) * 16 * 512, kbuf[cur ^ 1], t);
    if (kact) {
      if (c == 0) { sc[0] = 0.f; sc[1] = 0.f; sc[2] = 0.f; sc[3] = 0.f; }
#pragma unroll
      for (int aa = 0; aa < 16; aa++) {
        const int a = c * 16 + aa;
        const float qv = sQ2[tq][a];
        const float vv = sV2[a];
        float4 kp4 = *(const float4*)&kbuf[cur][aa * 512 + td4];
        sc[0] -= vv * __fdividef(1.0f, 1.0f + __expf(qv + kp4.x));
        sc[1] -= vv * __fdividef(1.0f, 1.0f + __expf(qv + kp4.y));
        sc[2] -= vv * __fdividef(1.0f, 1.0f + __expf(qv + kp4.z));
        sc[3] -= vv * __fdividef(1.0f, 1.0f + __expf(qv + kp4.w));
      }
    }
    __syncthreads();
    cur ^= 1;
  }

  // mask tail of a partially-valid quad
  if (kact) {
#pragma unroll
    for (int j = 1; j < 4; j++)
      if (4 * tk + j >= klen) sc[j] = NEGV;
  }

  // ---- softmax over 512 (per q row; rows on waves {0,1} and {2,3}) ----
  const int w = t >> 6;
  float lm = fmaxf(fmaxf(sc[0], sc[1]), fmaxf(sc[2], sc[3]));
#pragma unroll
  for (int off = 32; off > 0; off >>= 1) lm = fmaxf(lm, __shfl_xor(lm, off));
  if ((t & 63) == 0) red[w] = lm;
  __syncthreads();
  const float M = fmaxf(red[tq * 2], red[tq * 2 + 1]);

  float e[4];
#pragma unroll
  for (int j = 0; j < 4; j++) e[j] = __expf(sc[j] - M);
  float ls = (e[0] + e[1]) + (e[2] + e[3]);
#pragma unroll
  for (int off = 32; off > 0; off >>= 1) ls += __shfl_xor(ls, off);
  if ((t & 63) == 0) red[4 + w] = ls;
  __syncthreads();
  const float S = red[4 + tq * 2] + red[4 + tq * 2 + 1];
  const float rinv = __fdividef(1.0f, S);

#pragma unroll
  for (int j = 0; j < 4; j++) sW[tq][4 * tk + j] = e[j] * rinv;

  // ---- PV phase: out[q][d] = sum_k w[k]*kv[k][d] ----
  const int nck = (klen + 15) >> 4;
  stage32k(kvb, kbuf[0], t);
  __syncthreads();   // covers sW too

  float4 acc = make_float4(0.f, 0.f, 0.f, 0.f);
  cur = 0;
#pragma unroll 1
  for (int c = 0; c < nck; c++) {
    if (c + 1 < nck) stage32k(kvb + (size_t)(c + 1) * 16 * 512, kbuf[cur ^ 1], t);
#pragma unroll
    for (int kk = 0; kk < 16; kk++) {
      const float wgt = sW[tq][c * 16 + kk];
      float4 x = *(const float4*)&kbuf[cur][kk * 512 + td4];
      acc.x += wgt * x.x; acc.y += wgt * x.y;
      acc.z += wgt * x.z; acc.w += wgt * x.w;
    }
    __syncthreads();
    cur ^= 1;
  }

  if (act1 || tq == 0) {
    *(float4*)&outb[(size_t)tq * 512 + td4] = acc;
  } else {
    float4 m = *(const float4*)&kvsum[b * 512 + td4];
    m.x *= (1.0f / 512.0f); m.y *= (1.0f / 512.0f);
    m.z *= (1.0f / 512.0f); m.w *= (1.0f / 512.0f);
    *(float4*)&outb[(size_t)512 + td4] = m;
  }
}

// ---------------------------------------------------------------------------
extern "C" void kernel_launch(void* const* d_in, const int* in_sizes, int n_in,
                              void* d_out, int out_size, void* d_ws, size_t ws_size,
                              hipStream_t stream)
{
  const float* query = (const float*)d_in[0];  // [8][128][512]
  const float* kv    = (const float*)d_in[1];  // [8][512][512]
  const float* W     = (const float*)d_in[2];  // [256][1024]
  const float* bbias = (const float*)d_in[3];  // [256]
  const float* v     = (const float*)d_in[4];  // [256]
  const int*   qlen  = (const int*)d_in[5];    // [8]
  const int*   klen  = (const int*)d_in[6];    // [8]
  float* out = (float*)d_out;                  // [8][128][512]

  float* qp    = (float*)d_ws;            // 1024*256
  float* kpT   = qp + 1024 * 256;         // 8*256*512
  float* kvsum = kpT + 8 * 256 * 512;     // 8*512

  hipMemsetAsync(kvsum, 0, 8 * 512 * sizeof(float), stream);

  proj_gemm<<<dim3(320), 256, 0, stream>>>(query, kv, W, bbias, qp, kpT);

  kv_colsum<<<dim3(8, 8), 256, 0, stream>>>(kv, kvsum);

  attn_fused<<<dim3(64, 8), 256, 0, stream>>>(
      qp, kpT, kvsum, kv, v, qlen, klen, out);
}

// Round 3
// 124.768 us; speedup vs baseline: 1.4882x; 1.1838x over previous
//
#include <hip/hip_runtime.h>

#define NEGV (-10000000000.0f)
#define BK 16

// ---------------------------------------------------------------------------
// generic 256-thread f32 tile GEMM: C[m][n] = (sum_d A[m][d]*B[n][d] + bias[n])*2
// TM x TN tile, RM x RN micro-tile, K loop in BK chunks. sA/sB are LDS scratch.
// ---------------------------------------------------------------------------
template <int TM, int TN, int RM, int RN>
__device__ __forceinline__ void gemm_tile(
    const float* __restrict__ A, int lda,
    const float* __restrict__ B, int ldb,
    float* __restrict__ C, int ldc,
    const float* __restrict__ bias,
    int bm, int bn, int t, float* sA, float* sB)
{
  constexpr int LA = TM + 4, LB = TN + 4;
  constexpr int NTN = TN / RN;
  const int ty = t / NTN, tx = t % NTN;
  float acc[RM][RN] = {};

  for (int k0 = 0; k0 < 512; k0 += BK) {
#pragma unroll
    for (int e = t; e < TM * BK; e += 256) {
      int r = e >> 4, kk = e & 15;
      sA[kk * LA + r] = A[(size_t)(bm + r) * lda + k0 + kk];
    }
#pragma unroll
    for (int e = t; e < TN * BK; e += 256) {
      int r = e >> 4, kk = e & 15;
      sB[kk * LB + r] = B[(size_t)(bn + r) * ldb + k0 + kk];
    }
    __syncthreads();
#pragma unroll
    for (int kk = 0; kk < BK; kk++) {
      float ar[RM], br[RN];
#pragma unroll
      for (int i = 0; i < RM; i++) ar[i] = sA[kk * LA + ty * RM + i];
#pragma unroll
      for (int j = 0; j < RN; j++) br[j] = sB[kk * LB + tx * RN + j];
#pragma unroll
      for (int i = 0; i < RM; i++)
#pragma unroll
        for (int j = 0; j < RN; j++) acc[i][j] += ar[i] * br[j];
    }
    __syncthreads();
  }

#pragma unroll
  for (int i = 0; i < RM; i++) {
    int m = bm + ty * RM + i;
#pragma unroll
    for (int j = 0; j < RN; j++) {
      int n = bn + tx * RN + j;
      float bv = bias ? bias[n] : 0.0f;
      C[(size_t)m * ldc + n] = (acc[i][j] + bv) * 2.0f;  // pre-double for exp(2x)
    }
  }
}

// one launch: qp gemm (128 blocks) + kpT gemm (512) + kv colsum (256)
__global__ __launch_bounds__(256) void proj_all(
    const float* __restrict__ query, const float* __restrict__ kv,
    const float* __restrict__ W, const float* __restrict__ bias,
    float* __restrict__ qp, float* __restrict__ kpT, float* __restrict__ kvsum)
{
  __shared__ float smem[2 * BK * 68];
  float* sA = smem;
  float* sB = smem + BK * 68;
  const int id = blockIdx.x, t = threadIdx.x;

  if (id < 128) {
    // qp[m][a] = (query[m][:]·Wq[a][:] + b[a])*2 ; M=1024, N=256, 64x32 tiles
    int mi = id & 15, ni = id >> 4;
    gemm_tile<64, 32, 4, 2>(query, 512, W, 1024, qp, 256, bias,
                            mi * 64, ni * 32, t, sA, sB);
  } else if (id < 640) {
    // kpT[b][a][k] = (Wk[a][:]·kv[b][k][:])*2 ; M=256(a), N=512(k), 32x64 tiles
    int r = id - 128;
    int b = r >> 6, w = r & 63;
    gemm_tile<32, 64, 2, 4>(W + 512, 1024, kv + (size_t)b * 512 * 512, 512,
                            kpT + (size_t)b * 256 * 512, 512, nullptr,
                            (w & 7) * 32, (w >> 3) * 64, t, sA, sB);
  } else {
    // kvsum[b][d] += sum over 16 k rows
    int r = id - 640;
    int b = r >> 5, kt = r & 31;
    const float* p = kv + ((size_t)b * 512 + kt * 16) * 512;
    float s0 = 0.f, s1 = 0.f;
#pragma unroll
    for (int k = 0; k < 16; k++) {
      s0 += p[(size_t)k * 512 + t];
      s1 += p[(size_t)k * 512 + t + 256];
    }
    atomicAdd(&kvsum[b * 512 + t], s0);
    atomicAdd(&kvsum[b * 512 + t + 256], s1);
  }
}

// ---------------------------------------------------------------------------
// score kernel: scW[b][q][k] = -sum_a 2 v_a / (1 + eq[q][a]*ek[k][a])
// eq = exp(qp2), ek = exp(kpT2) (both pre-doubled so this equals exp(2(qp+kp))).
// block = 16 q x 64 k tile; wave w owns q rows w*4..w*4+3, lane owns one k.
// inactive tiles exit immediately -> work proportional to active area.
// ---------------------------------------------------------------------------
__global__ __launch_bounds__(256) void score_kernel(
    const float* __restrict__ qp2,    // [B*128][256]
    const float* __restrict__ kpT2,   // [B][256][512]
    const float* __restrict__ v,      // [256]
    const int* __restrict__ qlen_p, const int* __restrict__ klen_p,
    float* __restrict__ scW)          // [B][128][512]
{
  const int qt = blockIdx.x, kt = blockIdx.y, b = blockIdx.z;
  const int qlen = qlen_p[b], klen = klen_p[b];
  const int q0 = qt * 16, k0 = kt * 64;
  if (q0 >= qlen || k0 >= klen) return;

  __shared__ float sEq[16][256];
  __shared__ float sV2[256];
  const int t = threadIdx.x;

  sV2[t] = 2.0f * v[t];
#pragma unroll
  for (int q = 0; q < 16; q++)
    sEq[q][t] = __expf(qp2[(size_t)(b * 128 + q0 + q) * 256 + t]);
  __syncthreads();

  const int lane = t & 63, w = t >> 6;
  const float* kcol = kpT2 + (size_t)b * 256 * 512 + k0 + lane;

  float sc[4] = {0.f, 0.f, 0.f, 0.f};
#pragma unroll 8
  for (int a = 0; a < 256; a++) {
    float ek = __expf(kcol[(size_t)a * 512]);
    float vv = sV2[a];
#pragma unroll
    for (int j = 0; j < 4; j++) {
      float r = __builtin_amdgcn_rcpf(fmaf(sEq[w * 4 + j][a], ek, 1.0f));
      sc[j] = fmaf(-vv, r, sc[j]);
    }
  }

  const int k = k0 + lane;
  if (k < klen) {
#pragma unroll
    for (int j = 0; j < 4; j++) {
      int q = q0 + w * 4 + j;
      if (q < qlen) scW[(size_t)(b * 128 + q) * 512 + k] = sc[j];
    }
  }
}

// ---------------------------------------------------------------------------
// softmax + PV per (b, q-pair). tq = t>>7 (q row), td4 = (t&127)*4 (d quad).
// kv read directly (L2-resident), no staging barriers in the k loop.
// ---------------------------------------------------------------------------
__global__ __launch_bounds__(256) void softmax_pv(
    const float* __restrict__ scW,    // [B][128][512]
    const float* __restrict__ kvsum,  // [B][512]
    const float* __restrict__ kv,     // [B][512][512]
    const int* __restrict__ qlen_p, const int* __restrict__ klen_p,
    float* __restrict__ out)          // [B][128][512]
{
  const int b = blockIdx.y, q0 = blockIdx.x * 2, t = threadIdx.x;
  const int qlen = qlen_p[b], klen = klen_p[b];
  const int tq = t >> 7, td4 = (t & 127) * 4;

  float* outb = out + (size_t)(b * 128 + q0) * 512;

  if (q0 >= qlen) {  // both rows masked -> mean(kv[b]) over all 512
    float4 m = *(const float4*)&kvsum[b * 512 + td4];
    m.x *= (1.0f / 512.0f); m.y *= (1.0f / 512.0f);
    m.z *= (1.0f / 512.0f); m.w *= (1.0f / 512.0f);
    *(float4*)&outb[(size_t)tq * 512 + td4] = m;
    return;
  }
  const bool act1 = (q0 + 1) < qlen;

  __shared__ float sW[2][512];
  __shared__ float red[8];

  float s[4];
  if (tq == 0 || act1) {
    const float* srow = scW + (size_t)(b * 128 + q0 + tq) * 512;
    float4 s4 = *(const float4*)&srow[td4];
    s[0] = s4.x; s[1] = s4.y; s[2] = s4.z; s[3] = s4.w;
  } else {
    s[0] = s[1] = s[2] = s[3] = NEGV;
  }
#pragma unroll
  for (int j = 0; j < 4; j++)
    if (td4 + j >= klen) s[j] = NEGV;

  // row softmax: row tq lives on waves {2tq, 2tq+1}
  const int w = t >> 6;
  float lm = fmaxf(fmaxf(s[0], s[1]), fmaxf(s[2], s[3]));
#pragma unroll
  for (int off = 32; off > 0; off >>= 1) lm = fmaxf(lm, __shfl_xor(lm, off));
  if ((t & 63) == 0) red[w] = lm;
  __syncthreads();
  const float M = fmaxf(red[tq * 2], red[tq * 2 + 1]);

  float e[4];
#pragma unroll
  for (int j = 0; j < 4; j++) e[j] = __expf(s[j] - M);
  float ls = (e[0] + e[1]) + (e[2] + e[3]);
#pragma unroll
  for (int off = 32; off > 0; off >>= 1) ls += __shfl_xor(ls, off);
  if ((t & 63) == 0) red[4 + w] = ls;
  __syncthreads();
  const float S = red[4 + tq * 2] + red[4 + tq * 2 + 1];
  const float rinv = __fdividef(1.0f, S);

#pragma unroll
  for (int j = 0; j < 4; j++) sW[tq][td4 + j] = e[j] * rinv;
  __syncthreads();

  const float* kvb = kv + (size_t)b * 512 * 512;
  float4 acc = make_float4(0.f, 0.f, 0.f, 0.f);
#pragma unroll 4
  for (int k = 0; k < klen; k++) {
    float wg = sW[tq][k];
    float4 x = *(const float4*)&kvb[(size_t)k * 512 + td4];
    acc.x += wg * x.x; acc.y += wg * x.y;
    acc.z += wg * x.z; acc.w += wg * x.w;
  }

  if (tq == 0 || act1) {
    *(float4*)&outb[(size_t)tq * 512 + td4] = acc;
  } else {
    float4 m = *(const float4*)&kvsum[b * 512 + td4];
    m.x *= (1.0f / 512.0f); m.y *= (1.0f / 512.0f);
    m.z *= (1.0f / 512.0f); m.w *= (1.0f / 512.0f);
    *(float4*)&outb[(size_t)512 + td4] = m;
  }
}

// ---------------------------------------------------------------------------
extern "C" void kernel_launch(void* const* d_in, const int* in_sizes, int n_in,
                              void* d_out, int out_size, void* d_ws, size_t ws_size,
                              hipStream_t stream)
{
  const float* query = (const float*)d_in[0];  // [8][128][512]
  const float* kv    = (const float*)d_in[1];  // [8][512][512]
  const float* W     = (const float*)d_in[2];  // [256][1024]
  const float* bbias = (const float*)d_in[3];  // [256]
  const float* v     = (const float*)d_in[4];  // [256]
  const int*   qlen  = (const int*)d_in[5];    // [8]
  const int*   klen  = (const int*)d_in[6];    // [8]
  float* out = (float*)d_out;                  // [8][128][512]

  float* qp    = (float*)d_ws;            // 1024*256
  float* kpT   = qp + 1024 * 256;         // 8*256*512
  float* kvsum = kpT + 8 * 256 * 512;     // 8*512
  float* scW   = kvsum + 8 * 512;         // 8*128*512

  hipMemsetAsync(kvsum, 0, 8 * 512 * sizeof(float), stream);

  proj_all<<<dim3(896), 256, 0, stream>>>(query, kv, W, bbias, qp, kpT, kvsum);

  score_kernel<<<dim3(8, 8, 8), 256, 0, stream>>>(
      qp, kpT, v, qlen, klen, scW);

  softmax_pv<<<dim3(64, 8), 256, 0, stream>>>(
      scW, kvsum, kv, qlen, klen, out);
}

// Round 4
// 81.650 us; speedup vs baseline: 2.2741x; 1.5281x over previous
//
#include <hip/hip_runtime.h>

#define NEGV (-10000000000.0f)

typedef unsigned short u16;
typedef __attribute__((ext_vector_type(8))) short bf16x8;
typedef __attribute__((ext_vector_type(4))) float f32x4;

// f32 -> bf16 round-to-nearest-even (inputs are finite)
__device__ __forceinline__ u16 f2bf(float f) {
  unsigned u = __builtin_bit_cast(unsigned, f);
  u += 0x7fff + ((u >> 16) & 1);
  return (u16)(u >> 16);
}

__device__ __forceinline__ void gload16(const u16* g, u16* l) {
  __builtin_amdgcn_global_load_lds(
      (const __attribute__((address_space(1))) void*)g,
      (__attribute__((address_space(3))) void*)l, 16, 0, 0);
}

// ---------------------------------------------------------------------------
// prep: bf16 conversion of query+W (blocks 0..63) and kv (+column sums,
// blocks 64..127).
// ---------------------------------------------------------------------------
__global__ __launch_bounds__(256) void prep(
    const float* __restrict__ query, const float* __restrict__ W,
    const float* __restrict__ kv,
    u16* __restrict__ qb16, u16* __restrict__ wb16,
    u16* __restrict__ kvb16, float* __restrict__ kvsum)
{
  const int id = blockIdx.x, t = threadIdx.x;
  if (id < 64) {
    int idx = id * 256 + t;      // float4 index over query(131072) ++ W(65536)
#pragma unroll
    for (int it = 0; it < 12; it++, idx += 16384) {
      const float4* src; u16* dst; int j;
      if (idx < 131072) { src = (const float4*)query; j = idx;          dst = qb16; }
      else              { src = (const float4*)W;     j = idx - 131072; dst = wb16; }
      float4 x = src[j];
      ushort4 o;
      o.x = f2bf(x.x); o.y = f2bf(x.y); o.z = f2bf(x.z); o.w = f2bf(x.w);
      *(ushort4*)&dst[(size_t)j * 4] = o;
    }
  } else {
    int r = id - 64;
    int b = r >> 3, kt = r & 7;              // 64 k-rows per block
    const float* src = kv + ((size_t)b * 512 + kt * 64) * 512;
    u16* dst = kvb16 + ((size_t)b * 512 + kt * 64) * 512;
    float s0 = 0.f, s1 = 0.f;
#pragma unroll 4
    for (int k = 0; k < 64; k++) {
      float2 x = *(const float2*)&src[(size_t)k * 512 + 2 * t];
      s0 += x.x; s1 += x.y;
      ushort2 o; o.x = f2bf(x.x); o.y = f2bf(x.y);
      *(ushort2*)&dst[(size_t)k * 512 + 2 * t] = o;
    }
    atomicAdd(&kvsum[b * 512 + 2 * t], s0);
    atomicAdd(&kvsum[b * 512 + 2 * t + 1], s1);
  }
}

// ---------------------------------------------------------------------------
// 64x64 bf16 MFMA NT tile: C[m][n] = (sum_k A[m][k]*B[n][k] + bias[n]) * 2
// 4 waves (2x2), each 32x32 via 2x2 16x16x32 fragments. BK=64.
// LDS staged with global_load_lds(16B); XOR swizzle (byte ^= (row&7)<<4)
// applied on the GLOBAL source and the LDS read (both-sides rule).
// ---------------------------------------------------------------------------
__device__ __forceinline__ void gemm_mfma64(
    const u16* __restrict__ A, int lda,
    const u16* __restrict__ B, int ldb,
    float* __restrict__ C, int ldc,
    const float* __restrict__ bias,
    int bm, int bn, int t, u16* sA, u16* sB)
{
  const int l = t & 63, w = t >> 6;
  const int wr = w >> 1, wc = w & 1;
  f32x4 acc[2][2] = {};

  const int srow = l >> 3;                  // row within 8-row segment
  const int scol = ((l & 7) ^ srow) << 3;   // inverse-swizzled source col (elems)

  for (int k0 = 0; k0 < 512; k0 += 64) {
#pragma unroll
    for (int i = 0; i < 4; i++) {
      int s = w * 4 + i;                    // 0..15, wave-uniform
      if (s < 8) {
        gload16(A + (size_t)(bm + s * 8 + srow) * lda + k0 + scol, sA + s * 512);
      } else {
        int s2 = s - 8;
        gload16(B + (size_t)(bn + s2 * 8 + srow) * ldb + k0 + scol, sB + s2 * 512);
      }
    }
    __syncthreads();
#pragma unroll
    for (int ks = 0; ks < 2; ks++) {
      bf16x8 af[2], bfr[2];
#pragma unroll
      for (int f = 0; f < 2; f++) {
        int row = wr * 32 + f * 16 + (l & 15);
        int cbA = ((ks * 32 + ((l >> 4) << 3)) << 1) ^ ((row & 7) << 4);
        af[f] = *(const bf16x8*)((const char*)sA + row * 128 + cbA);
        int col = wc * 32 + f * 16 + (l & 15);
        int cbB = ((ks * 32 + ((l >> 4) << 3)) << 1) ^ ((col & 7) << 4);
        bfr[f] = *(const bf16x8*)((const char*)sB + col * 128 + cbB);
      }
#pragma unroll
      for (int fm = 0; fm < 2; fm++)
#pragma unroll
        for (int fn = 0; fn < 2; fn++)
          acc[fm][fn] = __builtin_amdgcn_mfma_f32_16x16x32_bf16(
              af[fm], bfr[fn], acc[fm][fn], 0, 0, 0);
    }
    __syncthreads();
  }

#pragma unroll
  for (int fm = 0; fm < 2; fm++)
#pragma unroll
    for (int fn = 0; fn < 2; fn++) {
      int cn = bn + wc * 32 + fn * 16 + (l & 15);
      float bv = bias ? bias[cn] : 0.0f;
#pragma unroll
      for (int j = 0; j < 4; j++) {
        int rm = bm + wr * 32 + fm * 16 + (l >> 4) * 4 + j;
        C[(size_t)rm * ldc + cn] = (acc[fm][fn][j] + bv) * 2.0f;  // pre-double
      }
    }
}

// blocks 0..63: qp (1024x256). blocks 64..319: kpT (8 batches, 256a x 512k).
__global__ __launch_bounds__(256) void proj_mfma(
    const u16* __restrict__ qb16, const u16* __restrict__ wb16,
    const u16* __restrict__ kvb16, const float* __restrict__ bias,
    float* __restrict__ qp, float* __restrict__ kpT)
{
  __shared__ __align__(16) u16 sA[8 * 512];
  __shared__ __align__(16) u16 sB[8 * 512];
  const int id = blockIdx.x, t = threadIdx.x;
  if (id < 64) {
    gemm_mfma64(qb16, 512, wb16, 1024, qp, 256, bias,
                (id >> 2) * 64, (id & 3) * 64, t, sA, sB);
  } else {
    int r = id - 64;
    int b = r >> 5, w5 = r & 31;
    gemm_mfma64(wb16 + 512, 1024, kvb16 + (size_t)b * 512 * 512, 512,
                kpT + (size_t)b * 256 * 512, 512, nullptr,
                (w5 & 3) * 64, (w5 >> 2) * 64, t, sA, sB);
  }
}

// ---------------------------------------------------------------------------
// score kernel: scW[b][q][k] = -sum_a 2 v_a / (1 + eq[q][a]*ek[k][a])
// (true score minus a per-q constant -> identical softmax)
// ---------------------------------------------------------------------------
__global__ __launch_bounds__(256) void score_kernel(
    const float* __restrict__ qp2,    // [B*128][256], pre-doubled (+bias)
    const float* __restrict__ kpT2,   // [B][256][512], pre-doubled
    const float* __restrict__ v,      // [256]
    const int* __restrict__ qlen_p, const int* __restrict__ klen_p,
    float* __restrict__ scW)          // [B][128][512]
{
  const int qt = blockIdx.x, kt = blockIdx.y, b = blockIdx.z;
  const int qlen = qlen_p[b], klen = klen_p[b];
  const int q0 = qt * 16, k0 = kt * 64;
  if (q0 >= qlen || k0 >= klen) return;

  __shared__ float sEq[16][256];
  __shared__ float sV2[256];
  const int t = threadIdx.x;

  sV2[t] = 2.0f * v[t];
#pragma unroll
  for (int q = 0; q < 16; q++)
    sEq[q][t] = __expf(qp2[(size_t)(b * 128 + q0 + q) * 256 + t]);
  __syncthreads();

  const int lane = t & 63, w = t >> 6;
  const float* kcol = kpT2 + (size_t)b * 256 * 512 + k0 + lane;

  float sc[4] = {0.f, 0.f, 0.f, 0.f};
#pragma unroll 8
  for (int a = 0; a < 256; a++) {
    float ek = __expf(kcol[(size_t)a * 512]);
    float vv = sV2[a];
#pragma unroll
    for (int j = 0; j < 4; j++) {
      float r = __builtin_amdgcn_rcpf(fmaf(sEq[w * 4 + j][a], ek, 1.0f));
      sc[j] = fmaf(-vv, r, sc[j]);
    }
  }

  const int k = k0 + lane;
  if (k < klen) {
#pragma unroll
    for (int j = 0; j < 4; j++) {
      int q = q0 + w * 4 + j;
      if (q < qlen) scW[(size_t)(b * 128 + q) * 512 + k] = sc[j];
    }
  }
}

// ---------------------------------------------------------------------------
// softmax + PV per (b, q-pair). tq = t>>7, td4 = (t&127)*4.
// ---------------------------------------------------------------------------
__global__ __launch_bounds__(256) void softmax_pv(
    const float* __restrict__ scW,    // [B][128][512]
    const float* __restrict__ kvsum,  // [B][512]
    const float* __restrict__ kv,     // [B][512][512]
    const int* __restrict__ qlen_p, const int* __restrict__ klen_p,
    float* __restrict__ out)          // [B][128][512]
{
  const int b = blockIdx.y, q0 = blockIdx.x * 2, t = threadIdx.x;
  const int qlen = qlen_p[b], klen = klen_p[b];
  const int tq = t >> 7, td4 = (t & 127) * 4;

  float* outb = out + (size_t)(b * 128 + q0) * 512;

  if (q0 >= qlen) {  // both rows masked -> mean(kv[b])
    float4 m = *(const float4*)&kvsum[b * 512 + td4];
    m.x *= (1.0f / 512.0f); m.y *= (1.0f / 512.0f);
    m.z *= (1.0f / 512.0f); m.w *= (1.0f / 512.0f);
    *(float4*)&outb[(size_t)tq * 512 + td4] = m;
    return;
  }
  const bool act1 = (q0 + 1) < qlen;

  __shared__ float sW[2][512];
  __shared__ float red[8];

  float s[4];
  if (tq == 0 || act1) {
    const float* srow = scW + (size_t)(b * 128 + q0 + tq) * 512;
    float4 s4 = *(const float4*)&srow[td4];
    s[0] = s4.x; s[1] = s4.y; s[2] = s4.z; s[3] = s4.w;
  } else {
    s[0] = s[1] = s[2] = s[3] = NEGV;
  }
#pragma unroll
  for (int j = 0; j < 4; j++)
    if (td4 + j >= klen) s[j] = NEGV;

  const int w = t >> 6;
  float lm = fmaxf(fmaxf(s[0], s[1]), fmaxf(s[2], s[3]));
#pragma unroll
  for (int off = 32; off > 0; off >>= 1) lm = fmaxf(lm, __shfl_xor(lm, off));
  if ((t & 63) == 0) red[w] = lm;
  __syncthreads();
  const float M = fmaxf(red[tq * 2], red[tq * 2 + 1]);

  float e[4];
#pragma unroll
  for (int j = 0; j < 4; j++) e[j] = __expf(s[j] - M);
  float ls = (e[0] + e[1]) + (e[2] + e[3]);
#pragma unroll
  for (int off = 32; off > 0; off >>= 1) ls += __shfl_xor(ls, off);
  if ((t & 63) == 0) red[4 + w] = ls;
  __syncthreads();
  const float S = red[4 + tq * 2] + red[4 + tq * 2 + 1];
  const float rinv = __fdividef(1.0f, S);

#pragma unroll
  for (int j = 0; j < 4; j++) sW[tq][td4 + j] = e[j] * rinv;
  __syncthreads();

  const float* kvb = kv + (size_t)b * 512 * 512;
  float4 acc = make_float4(0.f, 0.f, 0.f, 0.f);
#pragma unroll 4
  for (int k = 0; k < klen; k++) {
    float wg = sW[tq][k];
    float4 x = *(const float4*)&kvb[(size_t)k * 512 + td4];
    acc.x += wg * x.x; acc.y += wg * x.y;
    acc.z += wg * x.z; acc.w += wg * x.w;
  }

  if (tq == 0 || act1) {
    *(float4*)&outb[(size_t)tq * 512 + td4] = acc;
  } else {
    float4 m = *(const float4*)&kvsum[b * 512 + td4];
    m.x *= (1.0f / 512.0f); m.y *= (1.0f / 512.0f);
    m.z *= (1.0f / 512.0f); m.w *= (1.0f / 512.0f);
    *(float4*)&outb[(size_t)512 + td4] = m;
  }
}

// ---------------------------------------------------------------------------
extern "C" void kernel_launch(void* const* d_in, const int* in_sizes, int n_in,
                              void* d_out, int out_size, void* d_ws, size_t ws_size,
                              hipStream_t stream)
{
  const float* query = (const float*)d_in[0];  // [8][128][512]
  const float* kv    = (const float*)d_in[1];  // [8][512][512]
  const float* W     = (const float*)d_in[2];  // [256][1024]
  const float* bbias = (const float*)d_in[3];  // [256]
  const float* v     = (const float*)d_in[4];  // [256]
  const int*   qlen  = (const int*)d_in[5];    // [8]
  const int*   klen  = (const int*)d_in[6];    // [8]
  float* out = (float*)d_out;                  // [8][128][512]

  float* qp    = (float*)d_ws;                 // 1024*256 f          (1MB)
  float* kpT   = qp + 1024 * 256;              // 8*256*512 f         (4MB)
  float* kvsum = kpT + 8 * 256 * 512;          // 8*512 f
  float* scW   = kvsum + 8 * 512;              // 8*128*512 f         (2MB)
  u16*   qb16  = (u16*)(scW + 8 * 128 * 512);  // 1024*512 u16        (1MB)
  u16*   wb16  = qb16 + 1024 * 512;            // 256*1024 u16        (0.5MB)
  u16*   kvb16 = wb16 + 256 * 1024;            // 8*512*512 u16       (4MB)

  hipMemsetAsync(kvsum, 0, 8 * 512 * sizeof(float), stream);

  prep<<<dim3(128), 256, 0, stream>>>(query, W, kv, qb16, wb16, kvb16, kvsum);

  proj_mfma<<<dim3(320), 256, 0, stream>>>(qb16, wb16, kvb16, bbias, qp, kpT);

  score_kernel<<<dim3(8, 8, 8), 256, 0, stream>>>(
      qp, kpT, v, qlen, klen, scW);

  softmax_pv<<<dim3(64, 8), 256, 0, stream>>>(
      scW, kvsum, kv, qlen, klen, out);
}

// Round 5
// 63.830 us; speedup vs baseline: 2.9090x; 1.2792x over previous
//
#include <hip/hip_runtime.h>

#define NEGV (-10000000000.0f)

typedef unsigned short u16;
typedef _Float16 __attribute__((ext_vector_type(8))) f16x8;
typedef __attribute__((ext_vector_type(4))) float f32x4;

// f32 -> fp16 (RNE, values are well within range)
__device__ __forceinline__ u16 f2fh(float f) {
  _Float16 h = (_Float16)f;
  return __builtin_bit_cast(u16, h);
}

__device__ __forceinline__ void gload16(const u16* g, u16* l) {
  __builtin_amdgcn_global_load_lds(
      (const __attribute__((address_space(1))) void*)g,
      (__attribute__((address_space(3))) void*)l, 16, 0, 0);
}

// ---------------------------------------------------------------------------
// prep: fp16 conversion of query+W (blocks 0..63); kv conversion + column
// sums (blocks 64..127). kvsum via register partials + LDS + atomicAdd.
// ---------------------------------------------------------------------------
__global__ __launch_bounds__(256) void prep(
    const float* __restrict__ query, const float* __restrict__ W,
    const float* __restrict__ kv,
    u16* __restrict__ qh, u16* __restrict__ wh,
    u16* __restrict__ kvh, float* __restrict__ kvsum)
{
  const int id = blockIdx.x, t = threadIdx.x;
  if (id < 64) {
    int idx = id * 256 + t;      // float4 index over query(131072) ++ W(65536)
#pragma unroll
    for (int it = 0; it < 12; it++, idx += 16384) {
      const float4* src; u16* dst; int j;
      if (idx < 131072) { src = (const float4*)query; j = idx;          dst = qh; }
      else              { src = (const float4*)W;     j = idx - 131072; dst = wh; }
      float4 x = src[j];
      ushort4 o;
      o.x = f2fh(x.x); o.y = f2fh(x.y); o.z = f2fh(x.z); o.w = f2fh(x.w);
      *(ushort4*)&dst[(size_t)j * 4] = o;
    }
  } else {
    __shared__ float sPart[128][4];
    const int r = id - 64;
    const int b = r >> 3, kt = r & 7;               // 64 k-rows per block
    const float4* src4 = (const float4*)(kv + ((size_t)b * 512 + kt * 64) * 512);
    ushort4* dst4 = (ushort4*)(kvh + ((size_t)b * 512 + kt * 64) * 512);
    float4 p = make_float4(0.f, 0.f, 0.f, 0.f);     // col4 = t&127 is fixed
#pragma unroll 8
    for (int i = 0; i < 32; i++) {
      int idx = i * 256 + t;
      float4 x = src4[idx];
      p.x += x.x; p.y += x.y; p.z += x.z; p.w += x.w;
      ushort4 o;
      o.x = f2fh(x.x); o.y = f2fh(x.y); o.z = f2fh(x.z); o.w = f2fh(x.w);
      dst4[idx] = o;
    }
    if (t >= 128) { sPart[t - 128][0] = p.x; sPart[t - 128][1] = p.y;
                    sPart[t - 128][2] = p.z; sPart[t - 128][3] = p.w; }
    __syncthreads();
    if (t < 128) {
      atomicAdd(&kvsum[b * 512 + t * 4 + 0], p.x + sPart[t][0]);
      atomicAdd(&kvsum[b * 512 + t * 4 + 1], p.y + sPart[t][1]);
      atomicAdd(&kvsum[b * 512 + t * 4 + 2], p.z + sPart[t][2]);
      atomicAdd(&kvsum[b * 512 + t * 4 + 3], p.w + sPart[t][3]);
    }
  }
}

// ---------------------------------------------------------------------------
// 64x64 fp16 MFMA NT tile; epilogue writes  exp(2*(acc + bias)).
// XOR swizzle on global source + LDS read (both-sides rule).
// ---------------------------------------------------------------------------
__device__ __forceinline__ void gemm_mfma64(
    const u16* __restrict__ A, int lda,
    const u16* __restrict__ B, int ldb,
    float* __restrict__ C, int ldc,
    const float* __restrict__ bias,
    int bm, int bn, int t, u16* sA, u16* sB)
{
  const int l = t & 63, w = t >> 6;
  const int wr = w >> 1, wc = w & 1;
  f32x4 acc[2][2] = {};

  const int srow = l >> 3;                  // row within 8-row segment
  const int scol = ((l & 7) ^ srow) << 3;   // inverse-swizzled source col (elems)

  for (int k0 = 0; k0 < 512; k0 += 64) {
#pragma unroll
    for (int i = 0; i < 4; i++) {
      int s = w * 4 + i;                    // 0..15, wave-uniform
      if (s < 8) {
        gload16(A + (size_t)(bm + s * 8 + srow) * lda + k0 + scol, sA + s * 512);
      } else {
        int s2 = s - 8;
        gload16(B + (size_t)(bn + s2 * 8 + srow) * ldb + k0 + scol, sB + s2 * 512);
      }
    }
    __syncthreads();
#pragma unroll
    for (int ks = 0; ks < 2; ks++) {
      f16x8 af[2], bfr[2];
#pragma unroll
      for (int f = 0; f < 2; f++) {
        int row = wr * 32 + f * 16 + (l & 15);
        int cbA = ((ks * 32 + ((l >> 4) << 3)) << 1) ^ ((row & 7) << 4);
        af[f] = *(const f16x8*)((const char*)sA + row * 128 + cbA);
        int col = wc * 32 + f * 16 + (l & 15);
        int cbB = ((ks * 32 + ((l >> 4) << 3)) << 1) ^ ((col & 7) << 4);
        bfr[f] = *(const f16x8*)((const char*)sB + col * 128 + cbB);
      }
#pragma unroll
      for (int fm = 0; fm < 2; fm++)
#pragma unroll
        for (int fn = 0; fn < 2; fn++)
          acc[fm][fn] = __builtin_amdgcn_mfma_f32_16x16x32_f16(
              af[fm], bfr[fn], acc[fm][fn], 0, 0, 0);
    }
    __syncthreads();
  }

#pragma unroll
  for (int fm = 0; fm < 2; fm++)
#pragma unroll
    for (int fn = 0; fn < 2; fn++) {
      int cn = bn + wc * 32 + fn * 16 + (l & 15);
      float bv = bias ? bias[cn] : 0.0f;
#pragma unroll
      for (int j = 0; j < 4; j++) {
        int rm = bm + wr * 32 + fm * 16 + (l >> 4) * 4 + j;
        C[(size_t)rm * ldc + cn] = __expf((acc[fm][fn][j] + bv) * 2.0f);
      }
    }
}

// blocks 0..63: qpE (1024x256). blocks 64..319: kpE (8 batches, 256a x 512k).
__global__ __launch_bounds__(256) void proj_mfma(
    const u16* __restrict__ qh, const u16* __restrict__ wh,
    const u16* __restrict__ kvh, const float* __restrict__ bias,
    float* __restrict__ qpE, float* __restrict__ kpE)
{
  __shared__ __align__(16) u16 sA[8 * 512];
  __shared__ __align__(16) u16 sB[8 * 512];
  const int id = blockIdx.x, t = threadIdx.x;
  if (id < 64) {
    gemm_mfma64(qh, 512, wh, 1024, qpE, 256, bias,
                (id >> 2) * 64, (id & 3) * 64, t, sA, sB);
  } else {
    int r = id - 64;
    int b = r >> 5, w5 = r & 31;
    gemm_mfma64(wh + 512, 1024, kvh + (size_t)b * 512 * 512, 512,
                kpE + (size_t)b * 256 * 512, 512, nullptr,
                (w5 & 3) * 64, (w5 >> 2) * 64, t, sA, sB);
  }
}

// ---------------------------------------------------------------------------
// score: scW[b][q][k] = -sum_a 2 v_a / (1 + eq[q][a]*ek[a][k])
// (= true score minus per-q constant -> identical softmax).
// block = 4 q-rows x 64 k; wave w owns row q0+w, lane owns one k.
// ---------------------------------------------------------------------------
__global__ __launch_bounds__(256) void score_kernel(
    const float* __restrict__ qpE,    // [B*128][256] = exp(2(qp+b))
    const float* __restrict__ kpE,    // [B][256][512] = exp(2kp)
    const float* __restrict__ v,      // [256]
    const int* __restrict__ qlen_p, const int* __restrict__ klen_p,
    float* __restrict__ scW)          // [B][128][512]
{
  const int qt = blockIdx.x, kt = blockIdx.y, b = blockIdx.z;
  const int qlen = qlen_p[b], klen = klen_p[b];
  const int q0 = qt * 4, k0 = kt * 64;
  if (q0 >= qlen || k0 >= klen) return;

  __shared__ float sEq[4][256];
  __shared__ float sV2[256];
  const int t = threadIdx.x;

  sV2[t] = 2.0f * v[t];
#pragma unroll
  for (int r = 0; r < 4; r++)
    sEq[r][t] = qpE[(size_t)(b * 128 + q0 + r) * 256 + t];
  __syncthreads();

  const int l = t & 63, w = t >> 6;
  const int q = q0 + w;
  if (q >= qlen) return;                       // no barriers after this

  const int k = k0 + l;
  const float* kcol = kpE + (size_t)b * 256 * 512 + k;

  float sc = 0.f;
#pragma unroll 8
  for (int a = 0; a < 256; a++) {
    float ek = kcol[(size_t)a * 512];
    float r = __builtin_amdgcn_rcpf(fmaf(sEq[w][a], ek, 1.0f));
    sc = fmaf(-sV2[a], r, sc);
  }

  if (k < klen) scW[(size_t)(b * 128 + q) * 512 + k] = sc;
}

// ---------------------------------------------------------------------------
// softmax + PV. Block = one q row (b, q). 4 waves: softmax block-wide, then
// each wave PVs a 128-wide k-chunk over all 512 d (fp16 kv), LDS combine.
// ---------------------------------------------------------------------------
__global__ __launch_bounds__(256) void softmax_pv(
    const float* __restrict__ scW,    // [B][128][512]
    const float* __restrict__ kvsum,  // [B][512]
    const u16* __restrict__ kvh,      // [B][512][512] fp16
    const int* __restrict__ qlen_p, const int* __restrict__ klen_p,
    float* __restrict__ out)          // [B][128][512]
{
  const int q = blockIdx.x, b = blockIdx.y, t = threadIdx.x;
  const int qlen = qlen_p[b], klen = klen_p[b];

  float* orow = out + (size_t)(b * 128 + q) * 512;

  if (q >= qlen) {  // masked row -> mean(kv[b]) over all 512
    float2 m = *(const float2*)&kvsum[b * 512 + 2 * t];
    m.x *= (1.0f / 512.0f); m.y *= (1.0f / 512.0f);
    *(float2*)&orow[2 * t] = m;
    return;
  }

  __shared__ float sW[512];
  __shared__ float sAcc[4][512];
  __shared__ float red[8];

  const int w = t >> 6, l = t & 63;
  const float* srow = scW + (size_t)(b * 128 + q) * 512;

  float s0 = (t < klen)       ? srow[t]       : NEGV;
  float s1 = (t + 256 < klen) ? srow[t + 256] : NEGV;

  float lm = fmaxf(s0, s1);
#pragma unroll
  for (int off = 32; off > 0; off >>= 1) lm = fmaxf(lm, __shfl_xor(lm, off));
  if (l == 0) red[w] = lm;
  __syncthreads();
  const float M = fmaxf(fmaxf(red[0], red[1]), fmaxf(red[2], red[3]));

  float e0 = __expf(s0 - M), e1 = __expf(s1 - M);
  float ls = e0 + e1;
#pragma unroll
  for (int off = 32; off > 0; off >>= 1) ls += __shfl_xor(ls, off);
  if (l == 0) red[4 + w] = ls;
  __syncthreads();
  const float S = (red[4] + red[5]) + (red[6] + red[7]);
  const float rinv = __fdividef(1.0f, S);

  sW[t] = e0 * rinv;
  sW[t + 256] = e1 * rinv;
  __syncthreads();

  // PV: wave w covers k in [w*128, min(w*128+128, klen)), lane owns d octet
  const int kb = w * 128;
  const int ke = min(kb + 128, klen);
  const u16* kvb = kvh + (size_t)b * 512 * 512 + l * 8;

  float4 accA = make_float4(0.f, 0.f, 0.f, 0.f);
  float4 accB = make_float4(0.f, 0.f, 0.f, 0.f);
#pragma unroll 4
  for (int k = kb; k < ke; k++) {
    float wg = sW[k];
    f16x8 x = *(const f16x8*)&kvb[(size_t)k * 512];
    accA.x += wg * (float)x[0]; accA.y += wg * (float)x[1];
    accA.z += wg * (float)x[2]; accA.w += wg * (float)x[3];
    accB.x += wg * (float)x[4]; accB.y += wg * (float)x[5];
    accB.z += wg * (float)x[6]; accB.w += wg * (float)x[7];
  }
  *(float4*)&sAcc[w][l * 8]     = accA;
  *(float4*)&sAcc[w][l * 8 + 4] = accB;
  __syncthreads();

  // combine: thread t -> d = t and t+256 (bank-friendly)
  float r0 = (sAcc[0][t] + sAcc[1][t]) + (sAcc[2][t] + sAcc[3][t]);
  float r1 = (sAcc[0][t + 256] + sAcc[1][t + 256]) +
             (sAcc[2][t + 256] + sAcc[3][t + 256]);
  orow[t] = r0;
  orow[t + 256] = r1;
}

// ---------------------------------------------------------------------------
extern "C" void kernel_launch(void* const* d_in, const int* in_sizes, int n_in,
                              void* d_out, int out_size, void* d_ws, size_t ws_size,
                              hipStream_t stream)
{
  const float* query = (const float*)d_in[0];  // [8][128][512]
  const float* kv    = (const float*)d_in[1];  // [8][512][512]
  const float* W     = (const float*)d_in[2];  // [256][1024]
  const float* bbias = (const float*)d_in[3];  // [256]
  const float* v     = (const float*)d_in[4];  // [256]
  const int*   qlen  = (const int*)d_in[5];    // [8]
  const int*   klen  = (const int*)d_in[6];    // [8]
  float* out = (float*)d_out;                  // [8][128][512]

  float* qpE   = (float*)d_ws;                 // 1024*256 f          (1MB)
  float* kpE   = qpE + 1024 * 256;             // 8*256*512 f         (4MB)
  float* kvsum = kpE + 8 * 256 * 512;          // 8*512 f
  float* scW   = kvsum + 8 * 512;              // 8*128*512 f         (2MB)
  u16*   qh    = (u16*)(scW + 8 * 128 * 512);  // 1024*512 u16        (1MB)
  u16*   wh    = qh + 1024 * 512;              // 256*1024 u16        (0.5MB)
  u16*   kvh   = wh + 256 * 1024;              // 8*512*512 u16       (4MB)

  hipMemsetAsync(kvsum, 0, 8 * 512 * sizeof(float), stream);

  prep<<<dim3(128), 256, 0, stream>>>(query, W, kv, qh, wh, kvh, kvsum);

  proj_mfma<<<dim3(320), 256, 0, stream>>>(qh, wh, kvh, bbias, qpE, kpE);

  score_kernel<<<dim3(32, 8, 8), 256, 0, stream>>>(
      qpE, kpE, v, qlen, klen, scW);

  softmax_pv<<<dim3(128, 8), 256, 0, stream>>>(
      scW, kvsum, kvh, qlen, klen, out);
}

// Round 6
// 52.073 us; speedup vs baseline: 3.5657x; 1.2258x over previous
//
#include <hip/hip_runtime.h>

#define NEGV (-10000000000.0f)

typedef unsigned short u16;
typedef _Float16 __attribute__((ext_vector_type(8))) f16x8;
typedef __attribute__((ext_vector_type(4))) float f32x4;

__device__ __forceinline__ u16 f2fh(float f) {
  _Float16 h = (_Float16)f;
  return __builtin_bit_cast(u16, h);
}

__device__ __forceinline__ void gload16(const u16* g, u16* l) {
  __builtin_amdgcn_global_load_lds(
      (const __attribute__((address_space(1))) void*)g,
      (__attribute__((address_space(3))) void*)l, 16, 0, 0);
}

// ---------------------------------------------------------------------------
// prep: blocks 0..63  : fp16 convert query + W
//       blocks 64..575: fp16 convert one 64x64 kv tile -> kvh [k][d]
//                       AND kvhT [d][k] (LDS transpose)
// ---------------------------------------------------------------------------
__global__ __launch_bounds__(256) void prep(
    const float* __restrict__ query, const float* __restrict__ W,
    const float* __restrict__ kv,
    u16* __restrict__ qh, u16* __restrict__ wh,
    u16* __restrict__ kvh, u16* __restrict__ kvhT)
{
  const int id = blockIdx.x, t = threadIdx.x;
  if (id < 64) {
    int idx = id * 256 + t;      // float4 index over query(131072) ++ W(65536)
#pragma unroll
    for (int it = 0; it < 12; it++, idx += 16384) {
      const float4* src; u16* dst; int j;
      if (idx < 131072) { src = (const float4*)query; j = idx;          dst = qh; }
      else              { src = (const float4*)W;     j = idx - 131072; dst = wh; }
      float4 x = src[j];
      ushort4 o;
      o.x = f2fh(x.x); o.y = f2fh(x.y); o.z = f2fh(x.z); o.w = f2fh(x.w);
      *(ushort4*)&dst[(size_t)j * 4] = o;
    }
    return;
  }

  __shared__ float sT[64][68];       // [d_local][k_local], padded
  const int tile = id - 64;          // 0..511
  const int b  = tile >> 6;
  const int kt = (tile >> 3) & 7;
  const int dt = tile & 7;
  const int r  = t >> 2;             // 0..63
  const int c4 = t & 3;

  const float4* src = (const float4*)(kv + ((size_t)b * 512 + kt * 64) * 512 + dt * 64);
  ushort4* dkvh = (ushort4*)(kvh + ((size_t)b * 512 + kt * 64) * 512 + dt * 64);

#pragma unroll
  for (int i = 0; i < 4; i++) {
    int j = c4 * 4 + i;              // f4 col within tile, 0..15
    float4 x = src[(size_t)r * 128 + j];
    ushort4 o;
    o.x = f2fh(x.x); o.y = f2fh(x.y); o.z = f2fh(x.z); o.w = f2fh(x.w);
    dkvh[(size_t)r * 128 + j] = o;
    sT[j * 4 + 0][r] = x.x; sT[j * 4 + 1][r] = x.y;
    sT[j * 4 + 2][r] = x.z; sT[j * 4 + 3][r] = x.w;
  }
  __syncthreads();

  u16* dT = kvhT + ((size_t)b * 512 + dt * 64) * 512 + (size_t)kt * 64;
#pragma unroll
  for (int i = 0; i < 4; i++) {
    int j = c4 * 4 + i;
    float4 x = *(const float4*)&sT[r][j * 4];   // d_local = r, k_local = j*4..
    ushort4 o;
    o.x = f2fh(x.x); o.y = f2fh(x.y); o.z = f2fh(x.z); o.w = f2fh(x.w);
    *(ushort4*)&dT[(size_t)r * 512 + j * 4] = o;
  }
}

// ---------------------------------------------------------------------------
// 64x64 fp16 MFMA NT tile: acc = sum_k A[m][k]*B[n][k].
// EXPOUT: C = exp(2*(acc+bias))  else  C = acc + bias.
// XOR swizzle on global source + LDS read (both-sides rule).
// ---------------------------------------------------------------------------
template <bool EXPOUT>
__device__ __forceinline__ void gemm_mfma64(
    const u16* __restrict__ A, int lda,
    const u16* __restrict__ B, int ldb,
    float* __restrict__ C, int ldc,
    const float* __restrict__ bias,
    int bm, int bn, int t, u16* sA, u16* sB)
{
  const int l = t & 63, w = t >> 6;
  const int wr = w >> 1, wc = w & 1;
  f32x4 acc[2][2] = {};

  const int srow = l >> 3;
  const int scol = ((l & 7) ^ srow) << 3;

  for (int k0 = 0; k0 < 512; k0 += 64) {
#pragma unroll
    for (int i = 0; i < 4; i++) {
      int s = w * 4 + i;
      if (s < 8) {
        gload16(A + (size_t)(bm + s * 8 + srow) * lda + k0 + scol, sA + s * 512);
      } else {
        int s2 = s - 8;
        gload16(B + (size_t)(bn + s2 * 8 + srow) * ldb + k0 + scol, sB + s2 * 512);
      }
    }
    __syncthreads();
#pragma unroll
    for (int ks = 0; ks < 2; ks++) {
      f16x8 af[2], bfr[2];
#pragma unroll
      for (int f = 0; f < 2; f++) {
        int row = wr * 32 + f * 16 + (l & 15);
        int cbA = ((ks * 32 + ((l >> 4) << 3)) << 1) ^ ((row & 7) << 4);
        af[f] = *(const f16x8*)((const char*)sA + row * 128 + cbA);
        int col = wc * 32 + f * 16 + (l & 15);
        int cbB = ((ks * 32 + ((l >> 4) << 3)) << 1) ^ ((col & 7) << 4);
        bfr[f] = *(const f16x8*)((const char*)sB + col * 128 + cbB);
      }
#pragma unroll
      for (int fm = 0; fm < 2; fm++)
#pragma unroll
        for (int fn = 0; fn < 2; fn++)
          acc[fm][fn] = __builtin_amdgcn_mfma_f32_16x16x32_f16(
              af[fm], bfr[fn], acc[fm][fn], 0, 0, 0);
    }
    __syncthreads();
  }

#pragma unroll
  for (int fm = 0; fm < 2; fm++)
#pragma unroll
    for (int fn = 0; fn < 2; fn++) {
      int cn = bn + wc * 32 + fn * 16 + (l & 15);
      float bv = bias ? bias[cn] : 0.0f;
#pragma unroll
      for (int j = 0; j < 4; j++) {
        int rm = bm + wr * 32 + fm * 16 + (l >> 4) * 4 + j;
        float val = acc[fm][fn][j] + bv;
        C[(size_t)rm * ldc + cn] = EXPOUT ? __expf(val * 2.0f) : val;
      }
    }
}

// blocks 0..63: qpE (1024x256). blocks 64..319: kpE (8 b, 256a x 512k).
__global__ __launch_bounds__(256) void proj_mfma(
    const u16* __restrict__ qh, const u16* __restrict__ wh,
    const u16* __restrict__ kvh, const float* __restrict__ bias,
    float* __restrict__ qpE, float* __restrict__ kpE)
{
  __shared__ __align__(16) u16 sA[8 * 512];
  __shared__ __align__(16) u16 sB[8 * 512];
  const int id = blockIdx.x, t = threadIdx.x;
  if (id < 64) {
    gemm_mfma64<true>(qh, 512, wh, 1024, qpE, 256, bias,
                      (id >> 2) * 64, (id & 3) * 64, t, sA, sB);
  } else {
    int r = id - 64;
    int b = r >> 5, w5 = r & 31;
    gemm_mfma64<true>(wh + 512, 1024, kvh + (size_t)b * 512 * 512, 512,
                      kpE + (size_t)b * 256 * 512, 512, nullptr,
                      (w5 & 3) * 64, (w5 >> 2) * 64, t, sA, sB);
  }
}

// ---------------------------------------------------------------------------
// score: scS[b][q][k] = -sum_a 2 v_a / (1 + eq[q][a]*ek[a][k])
// block = 4 q-rows x 256 k; wave w owns k-chunk [kt*256+w*64, +64), all 4 q.
// ---------------------------------------------------------------------------
__global__ __launch_bounds__(256) void score_kernel(
    const float* __restrict__ qpE,    // [B*128][256] = exp(2(qp+b))
    const float* __restrict__ kpE,    // [B][256][512] = exp(2kp)
    const float* __restrict__ v,      // [256]
    const int* __restrict__ qlen_p, const int* __restrict__ klen_p,
    float* __restrict__ scS)          // [B][128][512]
{
  const int q0 = blockIdx.x * 4, b = blockIdx.z;
  const int qlen = qlen_p[b], klen = klen_p[b];
  const int kbase = blockIdx.y * 256;
  if (q0 >= qlen || kbase >= klen) return;

  __shared__ float sEq[4][256];
  __shared__ float sV2[256];
  const int t = threadIdx.x;

  sV2[t] = 2.0f * v[t];
#pragma unroll
  for (int r = 0; r < 4; r++)
    sEq[r][t] = qpE[(size_t)(b * 128 + q0 + r) * 256 + t];
  __syncthreads();

  const int w = t >> 6, l = t & 63;
  const int kc = kbase + w * 64;
  if (kc >= klen) return;
  const int k = kc + l;

  const float* kcol = kpE + (size_t)b * 256 * 512 + k;

  float s0 = 0.f, s1 = 0.f, s2 = 0.f, s3 = 0.f;
#pragma unroll 8
  for (int a = 0; a < 256; a++) {
    float ek = kcol[(size_t)a * 512];
    float vv = sV2[a];
    float r0 = __builtin_amdgcn_rcpf(fmaf(sEq[0][a], ek, 1.0f));
    float r1 = __builtin_amdgcn_rcpf(fmaf(sEq[1][a], ek, 1.0f));
    float r2 = __builtin_amdgcn_rcpf(fmaf(sEq[2][a], ek, 1.0f));
    float r3 = __builtin_amdgcn_rcpf(fmaf(sEq[3][a], ek, 1.0f));
    s0 = fmaf(-vv, r0, s0);
    s1 = fmaf(-vv, r1, s1);
    s2 = fmaf(-vv, r2, s2);
    s3 = fmaf(-vv, r3, s3);
  }

  if (k < klen) {
    float* dst = scS + (size_t)(b * 128 + q0) * 512 + k;
    dst[0] = s0;
    if (q0 + 1 < qlen) dst[512] = s1;
    if (q0 + 2 < qlen) dst[1024] = s2;
    if (q0 + 3 < qlen) dst[1536] = s3;
  }
}

// ---------------------------------------------------------------------------
// softmax: P[b][q][k] fp16. One wave per q row (4 rows/block).
// masked q -> uniform 1/512 (reference semantics); k>=klen -> 0.
// ---------------------------------------------------------------------------
__global__ __launch_bounds__(256) void softmax_kernel(
    const float* __restrict__ scS,    // [B][128][512]
    const int* __restrict__ qlen_p, const int* __restrict__ klen_p,
    u16* __restrict__ P)              // [B][128][512] fp16
{
  const int b = blockIdx.y, t = threadIdx.x;
  const int q = blockIdx.x * 4 + (t >> 6);
  const int l = t & 63;
  const int qlen = qlen_p[b], klen = klen_p[b];

  u16* prow = P + (size_t)(b * 128 + q) * 512;

  if (q >= qlen) {                    // uniform attention over all 512
    f16x8 u;
#pragma unroll
    for (int i = 0; i < 8; i++) u[i] = (_Float16)(1.0f / 512.0f);
    *(f16x8*)&prow[l * 8] = u;
    return;
  }

  const float* srow = scS + (size_t)(b * 128 + q) * 512;
  float s[8];
  *(float4*)&s[0] = *(const float4*)&srow[l * 8];
  *(float4*)&s[4] = *(const float4*)&srow[l * 8 + 4];
#pragma unroll
  for (int i = 0; i < 8; i++)
    if (l * 8 + i >= klen) s[i] = NEGV;

  float m = s[0];
#pragma unroll
  for (int i = 1; i < 8; i++) m = fmaxf(m, s[i]);
#pragma unroll
  for (int off = 32; off > 0; off >>= 1) m = fmaxf(m, __shfl_xor(m, off));

  float e[8], sum = 0.f;
#pragma unroll
  for (int i = 0; i < 8; i++) { e[i] = __expf(s[i] - m); sum += e[i]; }
#pragma unroll
  for (int off = 32; off > 0; off >>= 1) sum += __shfl_xor(sum, off);
  const float rinv = __fdividef(1.0f, sum);

  f16x8 o;
#pragma unroll
  for (int i = 0; i < 8; i++) o[i] = (_Float16)(e[i] * rinv);
  *(f16x8*)&prow[l * 8] = o;
}

// pv: out[b] = P[b] @ kv[b]  (M=128 q, N=512 d, K=512 k), NT via kvhT.
__global__ __launch_bounds__(256) void pv_mfma(
    const u16* __restrict__ P, const u16* __restrict__ kvhT,
    float* __restrict__ out)
{
  __shared__ __align__(16) u16 sA[8 * 512];
  __shared__ __align__(16) u16 sB[8 * 512];
  const int id = blockIdx.x, t = threadIdx.x;
  const int b = id >> 4, r = id & 15;
  const int mt = r >> 3, nt = r & 7;
  gemm_mfma64<false>(P + (size_t)b * 128 * 512, 512,
                     kvhT + (size_t)b * 512 * 512, 512,
                     out + (size_t)b * 128 * 512, 512, nullptr,
                     mt * 64, nt * 64, t, sA, sB);
}

// ---------------------------------------------------------------------------
extern "C" void kernel_launch(void* const* d_in, const int* in_sizes, int n_in,
                              void* d_out, int out_size, void* d_ws, size_t ws_size,
                              hipStream_t stream)
{
  const float* query = (const float*)d_in[0];  // [8][128][512]
  const float* kv    = (const float*)d_in[1];  // [8][512][512]
  const float* W     = (const float*)d_in[2];  // [256][1024]
  const float* bbias = (const float*)d_in[3];  // [256]
  const float* v     = (const float*)d_in[4];  // [256]
  const int*   qlen  = (const int*)d_in[5];    // [8]
  const int*   klen  = (const int*)d_in[6];    // [8]
  float* out = (float*)d_out;                  // [8][128][512]

  // workspace layout with lifetime-based aliasing (total 14.5 MB):
  float* qpE  = (float*)d_ws;                  // 1MB   live: proj -> score
  float* kpE  = qpE + 1024 * 256;              // 4MB   live: proj -> score
  u16*   kvh  = (u16*)(kpE + 8 * 256 * 512);   // 4MB   live: prep -> proj
  float* scS  = (float*)kvh;                   // alias (2MB) live: score -> softmax
  u16*   kvhT = kvh + 8 * 512 * 512;           // 4MB   live: prep -> pv
  u16*   qh   = kvhT + 8 * 512 * 512;          // 1MB   live: prep -> proj
  u16*   P    = qh;                            // alias (1MB) live: softmax -> pv
  u16*   wh   = qh + 1024 * 512;               // 0.5MB live: prep -> proj

  prep<<<dim3(576), 256, 0, stream>>>(query, W, kv, qh, wh, kvh, kvhT);

  proj_mfma<<<dim3(320), 256, 0, stream>>>(qh, wh, kvh, bbias, qpE, kpE);

  score_kernel<<<dim3(32, 2, 8), 256, 0, stream>>>(
      qpE, kpE, v, qlen, klen, scS);

  softmax_kernel<<<dim3(32, 8), 256, 0, stream>>>(scS, qlen, klen, P);

  pv_mfma<<<dim3(128), 256, 0, stream>>>(P, kvhT, out);
}